// Round 7
// baseline (1440.509 us; speedup 1.0000x reference)
//
#include <hip/hip_runtime.h>
#include <hip/hip_bf16.h>
#include <cstdint>
#include <cstddef>

#define NPTS   4096
#define NPT    1024            // NPOINT (S)
#define NSAMP  32
#define NBATCH 16
#define MROWS  (NBATCH*NPT*NSAMP)   // 524288 rows for the conv layers
#define EPSV   1e-5f

typedef __attribute__((ext_vector_type(8))) short bfrag;   // 8 bf16 = 4 VGPRs
typedef __attribute__((ext_vector_type(4))) float f32x4;
typedef __attribute__((ext_vector_type(2))) float f32x2;

static __device__ __forceinline__ unsigned short f2bf(float f) {
  union { float f; unsigned u; } x; x.f = f;
  unsigned u = x.u;
  u += 0x7FFFu + ((u >> 16) & 1u);
  return (unsigned short)(u >> 16);
}
static __device__ __forceinline__ float bf2f(unsigned short h) {
  union { unsigned u; float f; } x; x.u = ((unsigned)h) << 16;
  return x.f;
}
// RNE f32x2 -> packed bf16x2 (single instruction)
static __device__ __forceinline__ unsigned cvt_pk_bf16(float lo, float hi) {
  unsigned r;
  asm("v_cvt_pk_bf16_f32 %0, %1, %2" : "=v"(r) : "v"(lo), "v"(hi));
  return r;
}
// CDNA packed dual-FP32 (IEEE RN, same as scalar v_add/v_mul)
static __device__ __forceinline__ f32x2 pk_add(f32x2 a, f32x2 b) {
  f32x2 d;
  asm("v_pk_add_f32 %0, %1, %2" : "=v"(d) : "v"(a), "v"(b));
  return d;
}
static __device__ __forceinline__ f32x2 pk_mul(f32x2 a, f32x2 b) {
  f32x2 d;
  asm("v_pk_mul_f32 %0, %1, %2" : "=v"(d) : "v"(a), "v"(b));
  return d;
}

// ---------------------------------------------------------------------------
// Kernel 0: convert weights to bf16 (W0 zero-padded to K=96).
// ---------------------------------------------------------------------------
__global__ __launch_bounds__(256) void prep_kernel(
    const float* __restrict__ w0, const float* __restrict__ w1,
    const float* __restrict__ w2, unsigned short* __restrict__ wb0,
    unsigned short* __restrict__ wb1, unsigned short* __restrict__ wb2) {
  const int tid = threadIdx.x;
  for (int i = tid; i < 64 * 96; i += 256) {
    const int o = i / 96, c = i % 96;
    wb0[i] = (c < 67) ? f2bf(w0[o * 67 + c]) : (unsigned short)0;
  }
  for (int i = tid; i < 64 * 64; i += 256) wb1[i] = f2bf(w1[i]);
  for (int i = tid; i < 128 * 64; i += 256) wb2[i] = f2bf(w2[i]);
}

// ---------------------------------------------------------------------------
// Kernel 1: farthest point sampling, v5.
// 256 threads (4 waves), 16 points/thread in REGISTERS (loaded from global
// once; no coord LDS at all). Per iteration:
//   - packed-FP32 distance update (v_pk_add/v_pk_mul; p+(-c) == p-c exact,
//     same (dx^2+dy^2)+dz^2 association as numpy; scalar v_min for dist)
//   - depth-4 (value,x,y,z) tree argmax, strict-> keep-left == first-max
//   - wave DPP value-max -> ballot -> readlane of winner COORDS
//   - one float4 slot per wave (max,x,y,z), double-buffered, ONE barrier
//   - combine 4 slots in wave order (strict->) -> next centroid coords
// The index is never materialized: tie-break order == (pair, tree-slot,
// lane, wave) position order. Centroid re-read from LDS eliminated.
// ---------------------------------------------------------------------------
#define FPS_T 256
#define PPT   (NPTS / FPS_T)   // 16 points = 8 f32x2 pairs

template <int CTRL>
static __device__ __forceinline__ float dpp_max_step(float v) {
  int t = __builtin_amdgcn_update_dpp(0, __float_as_int(v), CTRL, 0xF, 0xF, true);
  return fmaxf(v, __int_as_float(t));
}

__global__ __launch_bounds__(FPS_T) void fps_kernel(
    const float* __restrict__ xyz, float* __restrict__ out_newxyz) {
  __shared__ __align__(16) float olds[NPT * 3];
  __shared__ __align__(16) float4 sl[2][4];   // (max, x, y, z) per wave

  const int b = blockIdx.x;
  const int tid = threadIdx.x;
  const int wave = tid >> 6;
  const float* base = xyz + (size_t)b * NPTS * 3;

  // load my 16 points (48 consecutive floats) into registers
  float arr[48];
  {
    const float* src = base + tid * 48;
    #pragma unroll
    for (int i = 0; i < 12; ++i)
      *(float4*)&arr[4 * i] = *(const float4*)&src[4 * i];
  }
  f32x2 px2[8], py2[8], pz2[8], dist2[8];
  #pragma unroll
  for (int p = 0; p < 8; ++p) {
    px2[p] = f32x2{arr[6 * p + 0], arr[6 * p + 3]};
    py2[p] = f32x2{arr[6 * p + 1], arr[6 * p + 4]};
    pz2[p] = f32x2{arr[6 * p + 2], arr[6 * p + 5]};
    dist2[p] = f32x2{1e10f, 1e10f};
  }

  // initial centroid = point 0 (uniform broadcast load)
  float ccx = base[0], ccy = base[1], ccz = base[2];

  for (int it = 0; it < NPT; ++it) {
    if (tid == 0) {
      olds[3 * it + 0] = ccx;
      olds[3 * it + 1] = ccy;
      olds[3 * it + 2] = ccz;
    }
    if (it == NPT - 1) break;

    // packed distance update
    const f32x2 ncx = {-ccx, -ccx}, ncy = {-ccy, -ccy}, ncz = {-ccz, -ccz};
    #pragma unroll
    for (int p = 0; p < 8; ++p) {
      const f32x2 dx = pk_add(px2[p], ncx);
      const f32x2 dy = pk_add(py2[p], ncy);
      const f32x2 dz = pk_add(pz2[p], ncz);
      const f32x2 t1 = pk_mul(dx, dx);
      const f32x2 t2 = pk_mul(dy, dy);
      const f32x2 t3 = pk_mul(dz, dz);
      const f32x2 s = pk_add(pk_add(t1, t2), t3);
      f32x2 nd = dist2[p];
      nd.x = fminf(nd.x, s.x);
      nd.y = fminf(nd.y, s.y);
      dist2[p] = nd;
    }

    // (value, coord) tree argmax; strict >, keep-left == first max
    float tv[8], tx[8], ty[8], tz[8];
    #pragma unroll
    for (int p = 0; p < 8; ++p) {
      const f32x2 d2 = dist2[p];
      const bool g = d2.y > d2.x;
      tv[p] = g ? d2.y : d2.x;
      tx[p] = g ? px2[p].y : px2[p].x;
      ty[p] = g ? py2[p].y : py2[p].x;
      tz[p] = g ? pz2[p].y : pz2[p].x;
    }
    #pragma unroll
    for (int st = 4; st >= 1; st >>= 1) {
      #pragma unroll
      for (int p = 0; p < st; ++p) {
        const bool g = tv[p + st] > tv[p];
        tv[p] = g ? tv[p + st] : tv[p];
        tx[p] = g ? tx[p + st] : tx[p];
        ty[p] = g ? ty[p + st] : ty[p];
        tz[p] = g ? tz[p + st] : tz[p];
      }
    }

    // wave-wide max value (distances >= 0, bound_ctrl zero-fill safe)
    float m = tv[0];
    m = dpp_max_step<0x111>(m);   // row_shr:1
    m = dpp_max_step<0x112>(m);   // row_shr:2
    m = dpp_max_step<0x114>(m);   // row_shr:4
    m = dpp_max_step<0x118>(m);   // row_shr:8
    m = dpp_max_step<0x142>(m);   // row_bcast:15
    m = dpp_max_step<0x143>(m);   // row_bcast:31
    const float wmax =
        __int_as_float(__builtin_amdgcn_readlane(__float_as_int(m), 63));

    // lowest matching lane == lowest index; pull its coords
    const unsigned long long mask = __ballot(tv[0] == wmax);
    const int wl = __ffsll((long long)mask) - 1;
    const float bx =
        __int_as_float(__builtin_amdgcn_readlane(__float_as_int(tx[0]), wl));
    const float by =
        __int_as_float(__builtin_amdgcn_readlane(__float_as_int(ty[0]), wl));
    const float bz =
        __int_as_float(__builtin_amdgcn_readlane(__float_as_int(tz[0]), wl));

    const int buf = it & 1;
    if ((tid & 63) == 0) sl[buf][wave] = make_float4(wmax, bx, by, bz);
    __syncthreads();   // single barrier; double-buffered slots prevent WAR

    const float4 s0 = sl[buf][0], s1 = sl[buf][1];
    const float4 s2 = sl[buf][2], s3 = sl[buf][3];
    float bv = s0.x;
    ccx = s0.y; ccy = s0.z; ccz = s0.w;
    if (s1.x > bv) { bv = s1.x; ccx = s1.y; ccy = s1.z; ccz = s1.w; }
    if (s2.x > bv) { bv = s2.x; ccx = s2.y; ccy = s2.z; ccz = s2.w; }
    if (s3.x > bv) { bv = s3.x; ccx = s3.y; ccy = s3.z; ccz = s3.w; }
  }

  __syncthreads();
  float* outb = out_newxyz + (size_t)b * NPT * 3;
  for (int i = tid; i < NPT * 3 / 4; i += FPS_T)
    *(float4*)&outb[4 * i] = *(const float4*)&olds[4 * i];
}

// ---------------------------------------------------------------------------
// Kernel 2: ball query (unchanged).
// ---------------------------------------------------------------------------
__global__ __launch_bounds__(256) void ballquery_kernel(
    const float* __restrict__ xyz, const float* __restrict__ newxyz,
    int* __restrict__ gidx) {
  const int gw = (int)((blockIdx.x * 256 + threadIdx.x) >> 6);
  const int lane = threadIdx.x & 63;
  const int b = gw >> 10, s = gw & 1023;
  const float* base = xyz + (size_t)b * NPTS * 3;
  const float* c = newxyz + (size_t)(b * NPT + s) * 3;
  const float cx = c[0], cy = c[1], cz = c[2];
  const float R2 = (float)(0.2 * 0.2);
  int* g = gidx + (size_t)(b * NPT + s) * NSAMP;

  int count = 0;
  int first = -1;
  for (int ch = 0; ch < NPTS / 64; ++ch) {
    const int i = ch * 64 + lane;
    const float dx = __fsub_rn(base[3 * i + 0], cx);
    const float dy = __fsub_rn(base[3 * i + 1], cy);
    const float dz = __fsub_rn(base[3 * i + 2], cz);
    const float d = __fadd_rn(__fadd_rn(__fmul_rn(dx, dx), __fmul_rn(dy, dy)),
                              __fmul_rn(dz, dz));
    const bool pred = !(d > R2);
    const unsigned long long mask = __ballot(pred);
    if (mask) {
      if (count == 0) first = ch * 64 + (__ffsll((long long)mask) - 1);
      const int rank = __popcll(mask & ((1ull << lane) - 1ull));
      const int pos = count + rank;
      if (pred && pos < NSAMP) g[pos] = i;
      count += (int)__popcll(mask);
      if (count >= NSAMP) break;
    }
  }
  if (first < 0) first = 0;
  for (int j = count + lane; j < NSAMP; j += 64) g[j] = first;
}

// ---------------------------------------------------------------------------
// Kernel 3: layer-1 MFMA matmul (unchanged).
// ---------------------------------------------------------------------------
__global__ __launch_bounds__(256) void mm1_mfma_kernel(
    const float* __restrict__ xyz, const float* __restrict__ points,
    const float* __restrict__ newxyz, const int* __restrict__ gidx,
    const unsigned short* __restrict__ Wb, unsigned short* __restrict__ Y,
    float* __restrict__ psum, float* __restrict__ psq) {
  constexpr int KP = 104;
  __shared__ __align__(16) unsigned short As[64 * KP];
  __shared__ __align__(16) unsigned short ly[64 * 64];
  __shared__ float ssum[64], ssq[64];
  const int tid = threadIdx.x, bid = blockIdx.x;
  const size_t r0 = (size_t)bid * 64;

  {
    const int row = tid >> 2, q = tid & 3;
    const int gs = bid * 2 + (row >> 5);
    const int b = gs >> 10;
    const int k = row & 31;
    const int gpt = gidx[(size_t)gs * NSAMP + k];
    const float* px = xyz + ((size_t)b * NPTS + gpt) * 3;
    const float* pc = newxyz + (size_t)gs * 3;
    const float* pf = points + ((size_t)b * NPTS + gpt) * 64;
    float v[24];
    #pragma unroll
    for (int cc = 0; cc < 24; ++cc) {
      const int cch = q * 24 + cc;
      float val;
      if (cch < 3)       val = px[cch] - pc[cch];
      else if (cch < 67) val = pf[cch - 3];
      else               val = 0.f;
      v[cc] = val;
    }
    unsigned* dst = (unsigned*)&As[row * KP + q * 24];
    #pragma unroll
    for (int p = 0; p < 12; ++p) dst[p] = cvt_pk_bf16(v[2 * p], v[2 * p + 1]);
  }
  if (tid < 64) { ssum[tid] = 0.f; ssq[tid] = 0.f; }
  __syncthreads();

  const int wave = tid >> 6, lane = tid & 63;
  const int l15 = lane & 15, kq = lane >> 4;
  const unsigned short* abase = &As[(wave * 16 + l15) * KP + kq * 8];
  const bfrag a0 = *(const bfrag*)abase;
  const bfrag a1 = *(const bfrag*)(abase + 32);
  const bfrag a2 = *(const bfrag*)(abase + 64);

  #pragma unroll
  for (int nt = 0; nt < 4; ++nt) {
    const unsigned short* wsrc = Wb + (size_t)(nt * 16 + l15) * 96 + kq * 8;
    const bfrag b0 = *(const bfrag*)wsrc;
    const bfrag b1 = *(const bfrag*)(wsrc + 32);
    const bfrag b2 = *(const bfrag*)(wsrc + 64);
    f32x4 acc = {0.f, 0.f, 0.f, 0.f};
    acc = __builtin_amdgcn_mfma_f32_16x16x32_bf16(a0, b0, acc, 0, 0, 0);
    acc = __builtin_amdgcn_mfma_f32_16x16x32_bf16(a1, b1, acc, 0, 0, 0);
    acc = __builtin_amdgcn_mfma_f32_16x16x32_bf16(a2, b2, acc, 0, 0, 0);

    float s = acc[0] + acc[1] + acc[2] + acc[3];
    float q = acc[0]*acc[0] + acc[1]*acc[1] + acc[2]*acc[2] + acc[3]*acc[3];
    s += __shfl_xor(s, 16); q += __shfl_xor(q, 16);
    s += __shfl_xor(s, 32); q += __shfl_xor(q, 32);
    if (kq == 0) {
      atomicAdd(&ssum[nt * 16 + l15], s);
      atomicAdd(&ssq [nt * 16 + l15], q);
    }
    const unsigned p01 = cvt_pk_bf16(acc[0], acc[1]);
    const unsigned p23 = cvt_pk_bf16(acc[2], acc[3]);
    const int colo = nt * 16 + l15;
    const int rbase = wave * 16 + kq * 4;
    ly[(rbase + 0) * 64 + colo] = (unsigned short)(p01 & 0xffffu);
    ly[(rbase + 1) * 64 + colo] = (unsigned short)(p01 >> 16);
    ly[(rbase + 2) * 64 + colo] = (unsigned short)(p23 & 0xffffu);
    ly[(rbase + 3) * 64 + colo] = (unsigned short)(p23 >> 16);
  }
  __syncthreads();
  {
    const uint4* lsrc = (const uint4*)ly;
    uint4* gdst = (uint4*)(Y + r0 * 64);
    #pragma unroll
    for (int i = tid; i < 64 * 64 * 2 / 16; i += 256) gdst[i] = lsrc[i];
  }
  if (tid < 64) {
    psum[(size_t)bid * 64 + tid] = ssum[tid];
    psq [(size_t)bid * 64 + tid] = ssq [tid];
  }
}

// ---------------------------------------------------------------------------
// Kernels 5/7: layers 2 & 3 MFMA (unchanged).
// ---------------------------------------------------------------------------
static __device__ __forceinline__ bfrag affine_relu_frag(
    const unsigned short* __restrict__ src, const float* __restrict__ st,
    int c0) {
  union { bfrag f; unsigned u[4]; } r;
  const uint4 raw = *(const uint4*)src;
  const unsigned w[4] = {raw.x, raw.y, raw.z, raw.w};
  #pragma unroll
  for (int p = 0; p < 4; ++p) {
    const int c = c0 + 2 * p;
    float lo = bf2f((unsigned short)(w[p] & 0xffffu));
    float hi = bf2f((unsigned short)(w[p] >> 16));
    lo = fmaxf(fmaf(lo, st[2 * c + 0], st[2 * c + 1]), 0.f);
    hi = fmaxf(fmaf(hi, st[2 * c + 2], st[2 * c + 3]), 0.f);
    r.u[p] = cvt_pk_bf16(lo, hi);
  }
  return r.f;
}

template <int COUT, int WAVES>
__global__ __launch_bounds__(WAVES * 64) void mm_mfma_kernel(
    const unsigned short* __restrict__ Xin, const unsigned short* __restrict__ Wb,
    const float* __restrict__ stin, unsigned short* __restrict__ Y,
    float* __restrict__ psum, float* __restrict__ psq) {
  constexpr int NT = COUT / 16;
  constexpr int ROWS = WAVES * 16;
  __shared__ float ssum[COUT], ssq[COUT];
  __shared__ __align__(16) unsigned short ly[ROWS * COUT];
  const int tid = threadIdx.x, bid = blockIdx.x;
  const int wave = tid >> 6, lane = tid & 63;
  const int l15 = lane & 15, kq = lane >> 4;
  const size_t r0 = (size_t)bid * ROWS;
  if (tid < COUT) { ssum[tid] = 0.f; ssq[tid] = 0.f; }

  const int arow = wave * 16 + l15;
  const unsigned short* asrc = Xin + (r0 + arow) * 64 + kq * 8;
  const bfrag a0 = affine_relu_frag(asrc, stin, kq * 8);
  const bfrag a1 = affine_relu_frag(asrc + 32, stin, 32 + kq * 8);
  __syncthreads();

  #pragma unroll
  for (int nt = 0; nt < NT; ++nt) {
    const unsigned short* wsrc = Wb + (size_t)(nt * 16 + l15) * 64 + kq * 8;
    const bfrag b0 = *(const bfrag*)wsrc;
    const bfrag b1 = *(const bfrag*)(wsrc + 32);
    f32x4 acc = {0.f, 0.f, 0.f, 0.f};
    acc = __builtin_amdgcn_mfma_f32_16x16x32_bf16(a0, b0, acc, 0, 0, 0);
    acc = __builtin_amdgcn_mfma_f32_16x16x32_bf16(a1, b1, acc, 0, 0, 0);

    float s = acc[0] + acc[1] + acc[2] + acc[3];
    float q = acc[0]*acc[0] + acc[1]*acc[1] + acc[2]*acc[2] + acc[3]*acc[3];
    s += __shfl_xor(s, 16); q += __shfl_xor(q, 16);
    s += __shfl_xor(s, 32); q += __shfl_xor(q, 32);
    if (kq == 0) {
      atomicAdd(&ssum[nt * 16 + l15], s);
      atomicAdd(&ssq [nt * 16 + l15], q);
    }
    const unsigned p01 = cvt_pk_bf16(acc[0], acc[1]);
    const unsigned p23 = cvt_pk_bf16(acc[2], acc[3]);
    const int colo = nt * 16 + l15;
    const int rbase = wave * 16 + kq * 4;
    ly[(rbase + 0) * COUT + colo] = (unsigned short)(p01 & 0xffffu);
    ly[(rbase + 1) * COUT + colo] = (unsigned short)(p01 >> 16);
    ly[(rbase + 2) * COUT + colo] = (unsigned short)(p23 & 0xffffu);
    ly[(rbase + 3) * COUT + colo] = (unsigned short)(p23 >> 16);
  }
  __syncthreads();
  {
    const uint4* lsrc = (const uint4*)ly;
    uint4* gdst = (uint4*)(Y + r0 * COUT);
    #pragma unroll
    for (int i = tid; i < ROWS * COUT * 2 / 16; i += WAVES * 64) gdst[i] = lsrc[i];
  }
  if (tid < COUT) {
    psum[(size_t)bid * COUT + tid] = ssum[tid];
    psq [(size_t)bid * COUT + tid] = ssq [tid];
  }
}

// ---------------------------------------------------------------------------
// BN stats finalize (unchanged).
// ---------------------------------------------------------------------------
__global__ __launch_bounds__(256) void finalize_kernel(
    const float* __restrict__ psum, const float* __restrict__ psq,
    const float* __restrict__ gam, const float* __restrict__ bet,
    float* __restrict__ st, int C, int nb) {
  const int c = blockIdx.x, tid = threadIdx.x;
  float s = 0.f, q = 0.f;
  for (int i = tid; i < nb; i += 256) {
    s += psum[(size_t)i * C + c];
    q += psq [(size_t)i * C + c];
  }
  #pragma unroll
  for (int off = 32; off > 0; off >>= 1) {
    s += __shfl_down(s, off);
    q += __shfl_down(q, off);
  }
  __shared__ float as_[4], aq_[4];
  if ((tid & 63) == 0) { as_[tid >> 6] = s; aq_[tid >> 6] = q; }
  __syncthreads();
  if (tid == 0) {
    s = as_[0] + as_[1] + as_[2] + as_[3];
    q = aq_[0] + aq_[1] + aq_[2] + aq_[3];
    const float invM = 1.f / (float)MROWS;
    const float mean = s * invM;
    const float var = q * invM - mean * mean;
    const float inv = 1.f / sqrtf(var + EPSV);
    const float sc = gam[c] * inv;
    st[2 * c + 0] = sc;
    st[2 * c + 1] = bet[c] - mean * sc;
  }
}

// ---------------------------------------------------------------------------
// maxpool: BN3 affine + relu + max over 32 samples (unchanged).
// ---------------------------------------------------------------------------
__global__ __launch_bounds__(128) void maxpool_kernel(
    const unsigned short* __restrict__ Y3, const float* __restrict__ st,
    float* __restrict__ out) {
  const int bsi = blockIdx.x, c = threadIdx.x;
  const unsigned short* p = Y3 + (size_t)bsi * NSAMP * 128 + c;
  const float sc = st[2 * c], sh = st[2 * c + 1];
  float m = -1e30f;
  #pragma unroll 8
  for (int k = 0; k < NSAMP; ++k)
    m = fmaxf(m, fmaf(bf2f(p[(size_t)k * 128]), sc, sh));
  out[(size_t)bsi * 128 + c] = fmaxf(m, 0.f);
}

// ---------------------------------------------------------------------------
extern "C" void kernel_launch(void* const* d_in, const int* in_sizes, int n_in,
                              void* d_out, int out_size, void* d_ws, size_t ws_size,
                              hipStream_t stream) {
  (void)in_sizes; (void)n_in; (void)out_size; (void)ws_size;
  const float* xyz    = (const float*)d_in[0];
  const float* points = (const float*)d_in[1];
  const float* w0 = (const float*)d_in[2];
  const float* g0 = (const float*)d_in[4];
  const float* be0 = (const float*)d_in[5];
  const float* w1 = (const float*)d_in[6];
  const float* g1 = (const float*)d_in[8];
  const float* be1 = (const float*)d_in[9];
  const float* w2 = (const float*)d_in[10];
  const float* g2 = (const float*)d_in[12];
  const float* be2 = (const float*)d_in[13];

  float* out = (float*)d_out;
  float* newxyz = out;
  float* newpts = out + (size_t)NBATCH * NPT * 3;

  char* ws = (char*)d_ws;
  unsigned short* Y1 = (unsigned short*)ws;
  unsigned short* Y3 = (unsigned short*)ws;
  unsigned short* Y2 = (unsigned short*)(ws + 134217728);
  int*   gidx = (int*)  (ws + 201326592);
  float* psum = (float*)(ws + 203423744);
  float* psq  = (float*)(ws + 205520896);
  float* st   = (float*)(ws + 207618048);
  float* st1 = st, *st2 = st + 256, *st3 = st + 512;
  unsigned short* wb0 = (unsigned short*)(ws + 207621120);
  unsigned short* wb1 = (unsigned short*)(ws + 207621120 + 12288);
  unsigned short* wb2 = (unsigned short*)(ws + 207621120 + 12288 + 8192);

  prep_kernel<<<1, 256, 0, stream>>>(w0, w1, w2, wb0, wb1, wb2);
  fps_kernel<<<NBATCH, FPS_T, 0, stream>>>(xyz, newxyz);
  ballquery_kernel<<<(NBATCH * NPT) / 4, 256, 0, stream>>>(xyz, newxyz, gidx);
  mm1_mfma_kernel<<<MROWS / 64, 256, 0, stream>>>(xyz, points, newxyz, gidx, wb0, Y1, psum, psq);
  finalize_kernel<<<64, 256, 0, stream>>>(psum, psq, g0, be0, st1, 64, MROWS / 64);
  mm_mfma_kernel<64, 4><<<MROWS / 64, 256, 0, stream>>>(Y1, wb1, st1, Y2, psum, psq);
  finalize_kernel<<<64, 256, 0, stream>>>(psum, psq, g1, be1, st2, 64, MROWS / 64);
  mm_mfma_kernel<128, 8><<<MROWS / 128, 512, 0, stream>>>(Y2, wb2, st2, Y3, psum, psq);
  finalize_kernel<<<128, 256, 0, stream>>>(psum, psq, g2, be2, st3, 128, MROWS / 128);
  maxpool_kernel<<<NBATCH * NPT, 128, 0, stream>>>(Y3, st3, newpts);
}

// Round 8
// 904.370 us; speedup vs baseline: 1.5928x; 1.5928x over previous
//
#include <hip/hip_runtime.h>
#include <hip/hip_bf16.h>
#include <cstdint>
#include <cstddef>

#define NPTS   4096
#define NPT    1024            // NPOINT (S)
#define NSAMP  32
#define NBATCH 16
#define MROWS  (NBATCH*NPT*NSAMP)   // 524288 rows for the conv layers
#define EPSV   1e-5f

typedef __attribute__((ext_vector_type(8))) short bfrag;   // 8 bf16 = 4 VGPRs
typedef __attribute__((ext_vector_type(4))) float f32x4;

static __device__ __forceinline__ unsigned short f2bf(float f) {
  union { float f; unsigned u; } x; x.f = f;
  unsigned u = x.u;
  u += 0x7FFFu + ((u >> 16) & 1u);
  return (unsigned short)(u >> 16);
}
static __device__ __forceinline__ float bf2f(unsigned short h) {
  union { unsigned u; float f; } x; x.u = ((unsigned)h) << 16;
  return x.f;
}
// RNE f32x2 -> packed bf16x2 (single instruction)
static __device__ __forceinline__ unsigned cvt_pk_bf16(float lo, float hi) {
  unsigned r;
  asm("v_cvt_pk_bf16_f32 %0, %1, %2" : "=v"(r) : "v"(lo), "v"(hi));
  return r;
}

// ---------------------------------------------------------------------------
// Kernel 0: convert weights to bf16 (W0 zero-padded to K=96).
// ---------------------------------------------------------------------------
__global__ __launch_bounds__(256) void prep_kernel(
    const float* __restrict__ w0, const float* __restrict__ w1,
    const float* __restrict__ w2, unsigned short* __restrict__ wb0,
    unsigned short* __restrict__ wb1, unsigned short* __restrict__ wb2) {
  const int tid = threadIdx.x;
  for (int i = tid; i < 64 * 96; i += 256) {
    const int o = i / 96, c = i % 96;
    wb0[i] = (c < 67) ? f2bf(w0[o * 67 + c]) : (unsigned short)0;
  }
  for (int i = tid; i < 64 * 64; i += 256) wb1[i] = f2bf(w1[i]);
  for (int i = tid; i < 128 * 64; i += 256) wb2[i] = f2bf(w2[i]);
}

// ---------------------------------------------------------------------------
// Kernel 1: farthest point sampling — round-6 version (best measured: 569us).
// 256 threads (4 waves), 16 pts/thread in registers, DPP wave-max, exact
// ballot tie-break, double-buffered slots, ONE barrier/iter, LDS-staged
// centroid output. pk-f32 / coord-carrying variants measured SLOWER (r5/r7).
// ---------------------------------------------------------------------------
#define FPS_T 256
#define PPT   (NPTS / FPS_T)   // 16

template <int CTRL>
static __device__ __forceinline__ float dpp_max_step(float v) {
  int t = __builtin_amdgcn_update_dpp(0, __float_as_int(v), CTRL, 0xF, 0xF, true);
  return fmaxf(v, __int_as_float(t));
}

__global__ __launch_bounds__(FPS_T) void fps_kernel(
    const float* __restrict__ xyz, float* __restrict__ out_newxyz) {
  __shared__ __align__(16) float xs[NPTS];
  __shared__ __align__(16) float ys[NPTS];
  __shared__ __align__(16) float zs[NPTS];
  __shared__ __align__(16) float olds[NPT * 3];
  __shared__ __align__(16) uint2 sl[2][4];   // (bits(max), idx) per wave

  const int b = blockIdx.x;
  const int tid = threadIdx.x;
  const int wave = tid >> 6;
  const float* base = xyz + (size_t)b * NPTS * 3;
  for (int i = tid; i < NPTS; i += FPS_T) {
    xs[i] = base[3 * i + 0];
    ys[i] = base[3 * i + 1];
    zs[i] = base[3 * i + 2];
  }
  __syncthreads();

  const int p0 = tid * PPT;
  float px[PPT], py[PPT], pz[PPT], dist[PPT];
  #pragma unroll
  for (int i = 0; i < PPT; i += 4) {
    *(float4*)&px[i] = *(const float4*)&xs[p0 + i];
    *(float4*)&py[i] = *(const float4*)&ys[p0 + i];
    *(float4*)&pz[i] = *(const float4*)&zs[p0 + i];
  }
  #pragma unroll
  for (int i = 0; i < PPT; ++i) dist[i] = 1e10f;

  int cur = 0;
  for (int it = 0; it < NPT; ++it) {
    const float cx = xs[cur], cy = ys[cur], cz = zs[cur];
    if (tid == 0) {
      olds[3 * it + 0] = cx;
      olds[3 * it + 1] = cy;
      olds[3 * it + 2] = cz;
    }
    if (it == NPT - 1) break;

    float bestv = -1.f; int besti = p0;
    #pragma unroll
    for (int i = 0; i < PPT; ++i) {
      const float dx = __fsub_rn(px[i], cx);
      const float dy = __fsub_rn(py[i], cy);
      const float dz = __fsub_rn(pz[i], cz);
      const float d = __fadd_rn(__fadd_rn(__fmul_rn(dx, dx), __fmul_rn(dy, dy)),
                                __fmul_rn(dz, dz));
      const float nd = fminf(dist[i], d);
      dist[i] = nd;
      const bool g = nd > bestv;      // strict >: first max wins within thread
      bestv = g ? nd : bestv;
      besti = g ? (p0 + i) : besti;
    }

    // wave-wide max VALUE (distances >= 0, bound_ctrl zero-fill safe)
    float m = bestv;
    m = dpp_max_step<0x111>(m);   // row_shr:1
    m = dpp_max_step<0x112>(m);   // row_shr:2
    m = dpp_max_step<0x114>(m);   // row_shr:4
    m = dpp_max_step<0x118>(m);   // row_shr:8
    m = dpp_max_step<0x142>(m);   // row_bcast:15
    m = dpp_max_step<0x143>(m);   // row_bcast:31  -> lane 63 holds wave max
    const float wmax =
        __int_as_float(__builtin_amdgcn_readlane(__float_as_int(m), 63));

    // lowest lane matching wave max == lowest index in wave
    const unsigned long long mask = __ballot(bestv == wmax);
    const int wl = __ffsll((long long)mask) - 1;
    const int widx = __builtin_amdgcn_readlane(besti, wl);

    const int buf = it & 1;
    if ((tid & 63) == 0)
      sl[buf][wave] = make_uint2(__float_as_uint(wmax), (unsigned)widx);
    __syncthreads();   // single barrier; double-buffered slots prevent WAR

    // all threads combine the 4 wave winners (2x ds_read_b128 broadcast)
    const uint4* p4 = (const uint4*)&sl[buf][0];
    const uint4 q0 = p4[0], q1 = p4[1];
    float bv; int bi;
    {
      bv = __uint_as_float(q0.x); bi = (int)q0.y;
      const float v1 = __uint_as_float(q0.z);
      if (v1 > bv) { bv = v1; bi = (int)q0.w; }
      const float v2 = __uint_as_float(q1.x);
      if (v2 > bv) { bv = v2; bi = (int)q1.y; }
      const float v3 = __uint_as_float(q1.z);
      if (v3 > bv) { bv = v3; bi = (int)q1.w; }
    }
    cur = bi;
  }

  __syncthreads();
  float* outb = out_newxyz + (size_t)b * NPT * 3;
  for (int i = tid; i < NPT * 3 / 4; i += FPS_T)
    *(float4*)&outb[4 * i] = *(const float4*)&olds[4 * i];
}

// ---------------------------------------------------------------------------
// Kernel 2: ball query (unchanged).
// ---------------------------------------------------------------------------
__global__ __launch_bounds__(256) void ballquery_kernel(
    const float* __restrict__ xyz, const float* __restrict__ newxyz,
    int* __restrict__ gidx) {
  const int gw = (int)((blockIdx.x * 256 + threadIdx.x) >> 6);
  const int lane = threadIdx.x & 63;
  const int b = gw >> 10, s = gw & 1023;
  const float* base = xyz + (size_t)b * NPTS * 3;
  const float* c = newxyz + (size_t)(b * NPT + s) * 3;
  const float cx = c[0], cy = c[1], cz = c[2];
  const float R2 = (float)(0.2 * 0.2);
  int* g = gidx + (size_t)(b * NPT + s) * NSAMP;

  int count = 0;
  int first = -1;
  for (int ch = 0; ch < NPTS / 64; ++ch) {
    const int i = ch * 64 + lane;
    const float dx = __fsub_rn(base[3 * i + 0], cx);
    const float dy = __fsub_rn(base[3 * i + 1], cy);
    const float dz = __fsub_rn(base[3 * i + 2], cz);
    const float d = __fadd_rn(__fadd_rn(__fmul_rn(dx, dx), __fmul_rn(dy, dy)),
                              __fmul_rn(dz, dz));
    const bool pred = !(d > R2);
    const unsigned long long mask = __ballot(pred);
    if (mask) {
      if (count == 0) first = ch * 64 + (__ffsll((long long)mask) - 1);
      const int rank = __popcll(mask & ((1ull << lane) - 1ull));
      const int pos = count + rank;
      if (pred && pos < NSAMP) g[pos] = i;
      count += (int)__popcll(mask);
      if (count >= NSAMP) break;
    }
  }
  if (first < 0) first = 0;
  for (int j = count + lane; j < NSAMP; j += 64) g[j] = first;
}

// ---------------------------------------------------------------------------
// Kernel 3: layer-1 MFMA matmul (unchanged).
// ---------------------------------------------------------------------------
__global__ __launch_bounds__(256) void mm1_mfma_kernel(
    const float* __restrict__ xyz, const float* __restrict__ points,
    const float* __restrict__ newxyz, const int* __restrict__ gidx,
    const unsigned short* __restrict__ Wb, unsigned short* __restrict__ Y,
    float* __restrict__ psum, float* __restrict__ psq) {
  constexpr int KP = 104;
  __shared__ __align__(16) unsigned short As[64 * KP];
  __shared__ __align__(16) unsigned short ly[64 * 64];
  __shared__ float ssum[64], ssq[64];
  const int tid = threadIdx.x, bid = blockIdx.x;
  const size_t r0 = (size_t)bid * 64;

  {
    const int row = tid >> 2, q = tid & 3;
    const int gs = bid * 2 + (row >> 5);
    const int b = gs >> 10;
    const int k = row & 31;
    const int gpt = gidx[(size_t)gs * NSAMP + k];
    const float* px = xyz + ((size_t)b * NPTS + gpt) * 3;
    const float* pc = newxyz + (size_t)gs * 3;
    const float* pf = points + ((size_t)b * NPTS + gpt) * 64;
    float v[24];
    #pragma unroll
    for (int cc = 0; cc < 24; ++cc) {
      const int cch = q * 24 + cc;
      float val;
      if (cch < 3)       val = px[cch] - pc[cch];
      else if (cch < 67) val = pf[cch - 3];
      else               val = 0.f;
      v[cc] = val;
    }
    unsigned* dst = (unsigned*)&As[row * KP + q * 24];
    #pragma unroll
    for (int p = 0; p < 12; ++p) dst[p] = cvt_pk_bf16(v[2 * p], v[2 * p + 1]);
  }
  if (tid < 64) { ssum[tid] = 0.f; ssq[tid] = 0.f; }
  __syncthreads();

  const int wave = tid >> 6, lane = tid & 63;
  const int l15 = lane & 15, kq = lane >> 4;
  const unsigned short* abase = &As[(wave * 16 + l15) * KP + kq * 8];
  const bfrag a0 = *(const bfrag*)abase;
  const bfrag a1 = *(const bfrag*)(abase + 32);
  const bfrag a2 = *(const bfrag*)(abase + 64);

  #pragma unroll
  for (int nt = 0; nt < 4; ++nt) {
    const unsigned short* wsrc = Wb + (size_t)(nt * 16 + l15) * 96 + kq * 8;
    const bfrag b0 = *(const bfrag*)wsrc;
    const bfrag b1 = *(const bfrag*)(wsrc + 32);
    const bfrag b2 = *(const bfrag*)(wsrc + 64);
    f32x4 acc = {0.f, 0.f, 0.f, 0.f};
    acc = __builtin_amdgcn_mfma_f32_16x16x32_bf16(a0, b0, acc, 0, 0, 0);
    acc = __builtin_amdgcn_mfma_f32_16x16x32_bf16(a1, b1, acc, 0, 0, 0);
    acc = __builtin_amdgcn_mfma_f32_16x16x32_bf16(a2, b2, acc, 0, 0, 0);

    float s = acc[0] + acc[1] + acc[2] + acc[3];
    float q = acc[0]*acc[0] + acc[1]*acc[1] + acc[2]*acc[2] + acc[3]*acc[3];
    s += __shfl_xor(s, 16); q += __shfl_xor(q, 16);
    s += __shfl_xor(s, 32); q += __shfl_xor(q, 32);
    if (kq == 0) {
      atomicAdd(&ssum[nt * 16 + l15], s);
      atomicAdd(&ssq [nt * 16 + l15], q);
    }
    const unsigned p01 = cvt_pk_bf16(acc[0], acc[1]);
    const unsigned p23 = cvt_pk_bf16(acc[2], acc[3]);
    const int colo = nt * 16 + l15;
    const int rbase = wave * 16 + kq * 4;
    ly[(rbase + 0) * 64 + colo] = (unsigned short)(p01 & 0xffffu);
    ly[(rbase + 1) * 64 + colo] = (unsigned short)(p01 >> 16);
    ly[(rbase + 2) * 64 + colo] = (unsigned short)(p23 & 0xffffu);
    ly[(rbase + 3) * 64 + colo] = (unsigned short)(p23 >> 16);
  }
  __syncthreads();
  {
    const uint4* lsrc = (const uint4*)ly;
    uint4* gdst = (uint4*)(Y + r0 * 64);
    #pragma unroll
    for (int i = tid; i < 64 * 64 * 2 / 16; i += 256) gdst[i] = lsrc[i];
  }
  if (tid < 64) {
    psum[(size_t)bid * 64 + tid] = ssum[tid];
    psq [(size_t)bid * 64 + tid] = ssq [tid];
  }
}

// ---------------------------------------------------------------------------
// Layer 2 MFMA (unchanged).
// ---------------------------------------------------------------------------
static __device__ __forceinline__ bfrag affine_relu_frag(
    const unsigned short* __restrict__ src, const float* __restrict__ st,
    int c0) {
  union { bfrag f; unsigned u[4]; } r;
  const uint4 raw = *(const uint4*)src;
  const unsigned w[4] = {raw.x, raw.y, raw.z, raw.w};
  #pragma unroll
  for (int p = 0; p < 4; ++p) {
    const int c = c0 + 2 * p;
    float lo = bf2f((unsigned short)(w[p] & 0xffffu));
    float hi = bf2f((unsigned short)(w[p] >> 16));
    lo = fmaxf(fmaf(lo, st[2 * c + 0], st[2 * c + 1]), 0.f);
    hi = fmaxf(fmaf(hi, st[2 * c + 2], st[2 * c + 3]), 0.f);
    r.u[p] = cvt_pk_bf16(lo, hi);
  }
  return r.f;
}

template <int COUT, int WAVES>
__global__ __launch_bounds__(WAVES * 64) void mm_mfma_kernel(
    const unsigned short* __restrict__ Xin, const unsigned short* __restrict__ Wb,
    const float* __restrict__ stin, unsigned short* __restrict__ Y,
    float* __restrict__ psum, float* __restrict__ psq) {
  constexpr int NT = COUT / 16;
  constexpr int ROWS = WAVES * 16;
  __shared__ float ssum[COUT], ssq[COUT];
  __shared__ __align__(16) unsigned short ly[ROWS * COUT];
  const int tid = threadIdx.x, bid = blockIdx.x;
  const int wave = tid >> 6, lane = tid & 63;
  const int l15 = lane & 15, kq = lane >> 4;
  const size_t r0 = (size_t)bid * ROWS;
  if (tid < COUT) { ssum[tid] = 0.f; ssq[tid] = 0.f; }

  const int arow = wave * 16 + l15;
  const unsigned short* asrc = Xin + (r0 + arow) * 64 + kq * 8;
  const bfrag a0 = affine_relu_frag(asrc, stin, kq * 8);
  const bfrag a1 = affine_relu_frag(asrc + 32, stin, 32 + kq * 8);
  __syncthreads();

  #pragma unroll
  for (int nt = 0; nt < NT; ++nt) {
    const unsigned short* wsrc = Wb + (size_t)(nt * 16 + l15) * 64 + kq * 8;
    const bfrag b0 = *(const bfrag*)wsrc;
    const bfrag b1 = *(const bfrag*)(wsrc + 32);
    f32x4 acc = {0.f, 0.f, 0.f, 0.f};
    acc = __builtin_amdgcn_mfma_f32_16x16x32_bf16(a0, b0, acc, 0, 0, 0);
    acc = __builtin_amdgcn_mfma_f32_16x16x32_bf16(a1, b1, acc, 0, 0, 0);

    float s = acc[0] + acc[1] + acc[2] + acc[3];
    float q = acc[0]*acc[0] + acc[1]*acc[1] + acc[2]*acc[2] + acc[3]*acc[3];
    s += __shfl_xor(s, 16); q += __shfl_xor(q, 16);
    s += __shfl_xor(s, 32); q += __shfl_xor(q, 32);
    if (kq == 0) {
      atomicAdd(&ssum[nt * 16 + l15], s);
      atomicAdd(&ssq [nt * 16 + l15], q);
    }
    const unsigned p01 = cvt_pk_bf16(acc[0], acc[1]);
    const unsigned p23 = cvt_pk_bf16(acc[2], acc[3]);
    const int colo = nt * 16 + l15;
    const int rbase = wave * 16 + kq * 4;
    ly[(rbase + 0) * COUT + colo] = (unsigned short)(p01 & 0xffffu);
    ly[(rbase + 1) * COUT + colo] = (unsigned short)(p01 >> 16);
    ly[(rbase + 2) * COUT + colo] = (unsigned short)(p23 & 0xffffu);
    ly[(rbase + 3) * COUT + colo] = (unsigned short)(p23 >> 16);
  }
  __syncthreads();
  {
    const uint4* lsrc = (const uint4*)ly;
    uint4* gdst = (uint4*)(Y + r0 * COUT);
    #pragma unroll
    for (int i = tid; i < ROWS * COUT * 2 / 16; i += WAVES * 64) gdst[i] = lsrc[i];
  }
  if (tid < COUT) {
    psum[(size_t)bid * COUT + tid] = ssum[tid];
    psq [(size_t)bid * COUT + tid] = ssq [tid];
  }
}

// ---------------------------------------------------------------------------
// Layer 3 MFMA + FUSED MAXPOOL. Raw (pre-BN) outputs are max-pooled over the
// 32 samples of each (b,s) group in-register + LDS; only the 8MB pooled
// tensor + BN stats are written. Valid because BN3 scale = g/sqrt(var+eps)
// > 0 (g == 1) and relu is monotone: max relu(affine(y)) ==
// relu(affine(max y)). Y3 (134MB write + 134MB read) is eliminated.
// Block: 512 threads / 8 waves / 128 rows = 4 (b,s) groups.
// ---------------------------------------------------------------------------
__global__ __launch_bounds__(512) void mm3_pool_kernel(
    const unsigned short* __restrict__ Xin, const unsigned short* __restrict__ Wb,
    const float* __restrict__ stin, float* __restrict__ pooled,
    float* __restrict__ psum, float* __restrict__ psq) {
  constexpr int COUT = 128, NT = 8;
  __shared__ float ssum[COUT], ssq[COUT];
  __shared__ float pm[8][COUT];           // per-wave 16-row max
  const int tid = threadIdx.x, bid = blockIdx.x;
  const int wave = tid >> 6, lane = tid & 63;
  const int l15 = lane & 15, kq = lane >> 4;
  const size_t r0 = (size_t)bid * 128;
  if (tid < COUT) { ssum[tid] = 0.f; ssq[tid] = 0.f; }

  const int arow = wave * 16 + l15;
  const unsigned short* asrc = Xin + (r0 + arow) * 64 + kq * 8;
  const bfrag a0 = affine_relu_frag(asrc, stin, kq * 8);
  const bfrag a1 = affine_relu_frag(asrc + 32, stin, 32 + kq * 8);
  __syncthreads();

  #pragma unroll
  for (int nt = 0; nt < NT; ++nt) {
    const unsigned short* wsrc = Wb + (size_t)(nt * 16 + l15) * 64 + kq * 8;
    const bfrag b0 = *(const bfrag*)wsrc;
    const bfrag b1 = *(const bfrag*)(wsrc + 32);
    f32x4 acc = {0.f, 0.f, 0.f, 0.f};
    acc = __builtin_amdgcn_mfma_f32_16x16x32_bf16(a0, b0, acc, 0, 0, 0);
    acc = __builtin_amdgcn_mfma_f32_16x16x32_bf16(a1, b1, acc, 0, 0, 0);

    float s = acc[0] + acc[1] + acc[2] + acc[3];
    float q = acc[0]*acc[0] + acc[1]*acc[1] + acc[2]*acc[2] + acc[3]*acc[3];
    s += __shfl_xor(s, 16); q += __shfl_xor(q, 16);
    s += __shfl_xor(s, 32); q += __shfl_xor(q, 32);
    // raw max over this lane's 4 rows, then over the wave's 16 rows
    float mx = fmaxf(fmaxf(acc[0], acc[1]), fmaxf(acc[2], acc[3]));
    mx = fmaxf(mx, __shfl_xor(mx, 16));
    mx = fmaxf(mx, __shfl_xor(mx, 32));
    if (kq == 0) {
      atomicAdd(&ssum[nt * 16 + l15], s);
      atomicAdd(&ssq [nt * 16 + l15], q);
      pm[wave][nt * 16 + l15] = mx;
    }
  }
  __syncthreads();
  // rows of wave 2g and 2g+1 are k=0..15 / 16..31 of group g -> pairwise max
  {
    const int g = tid >> 7, col = tid & 127;   // 512 threads = 4 groups x 128
    const float v = fmaxf(pm[2 * g][col], pm[2 * g + 1][col]);
    pooled[(r0 >> 5) * COUT + g * COUT + col] = v;   // (bid*4+g)*128+col
  }
  if (tid < COUT) {
    psum[(size_t)bid * COUT + tid] = ssum[tid];
    psq [(size_t)bid * COUT + tid] = ssq [tid];
  }
}

// ---------------------------------------------------------------------------
// BN stats finalize (unchanged).
// ---------------------------------------------------------------------------
__global__ __launch_bounds__(256) void finalize_kernel(
    const float* __restrict__ psum, const float* __restrict__ psq,
    const float* __restrict__ gam, const float* __restrict__ bet,
    float* __restrict__ st, int C, int nb) {
  const int c = blockIdx.x, tid = threadIdx.x;
  float s = 0.f, q = 0.f;
  for (int i = tid; i < nb; i += 256) {
    s += psum[(size_t)i * C + c];
    q += psq [(size_t)i * C + c];
  }
  #pragma unroll
  for (int off = 32; off > 0; off >>= 1) {
    s += __shfl_down(s, off);
    q += __shfl_down(q, off);
  }
  __shared__ float as_[4], aq_[4];
  if ((tid & 63) == 0) { as_[tid >> 6] = s; aq_[tid >> 6] = q; }
  __syncthreads();
  if (tid == 0) {
    s = as_[0] + as_[1] + as_[2] + as_[3];
    q = aq_[0] + aq_[1] + aq_[2] + aq_[3];
    const float invM = 1.f / (float)MROWS;
    const float mean = s * invM;
    const float var = q * invM - mean * mean;
    const float inv = 1.f / sqrtf(var + EPSV);
    const float sc = gam[c] * inv;
    st[2 * c + 0] = sc;
    st[2 * c + 1] = bet[c] - mean * sc;
  }
}

// ---------------------------------------------------------------------------
// Epilogue: BN3 affine + relu on the pooled tensor -> new_points (8MB->8MB).
// ---------------------------------------------------------------------------
__global__ __launch_bounds__(256) void bn_relu_kernel(
    const float* __restrict__ pooled, const float* __restrict__ st,
    float* __restrict__ out) {
  __shared__ float s_st[256];
  const int tid = threadIdx.x;
  s_st[tid] = st[tid];
  __syncthreads();
  const int n4 = NBATCH * NPT * 128 / 4;
  for (int i = blockIdx.x * 256 + tid; i < n4; i += gridDim.x * 256) {
    float4 v = ((const float4*)pooled)[i];
    const int c0 = (i * 4) & 127;
    v.x = fmaxf(fmaf(v.x, s_st[2 * c0 + 0], s_st[2 * c0 + 1]), 0.f);
    v.y = fmaxf(fmaf(v.y, s_st[2 * c0 + 2], s_st[2 * c0 + 3]), 0.f);
    v.z = fmaxf(fmaf(v.z, s_st[2 * c0 + 4], s_st[2 * c0 + 5]), 0.f);
    v.w = fmaxf(fmaf(v.w, s_st[2 * c0 + 6], s_st[2 * c0 + 7]), 0.f);
    ((float4*)out)[i] = v;
  }
}

// ---------------------------------------------------------------------------
extern "C" void kernel_launch(void* const* d_in, const int* in_sizes, int n_in,
                              void* d_out, int out_size, void* d_ws, size_t ws_size,
                              hipStream_t stream) {
  (void)in_sizes; (void)n_in; (void)out_size; (void)ws_size;
  const float* xyz    = (const float*)d_in[0];
  const float* points = (const float*)d_in[1];
  const float* w0 = (const float*)d_in[2];
  const float* g0 = (const float*)d_in[4];
  const float* be0 = (const float*)d_in[5];
  const float* w1 = (const float*)d_in[6];
  const float* g1 = (const float*)d_in[8];
  const float* be1 = (const float*)d_in[9];
  const float* w2 = (const float*)d_in[10];
  const float* g2 = (const float*)d_in[12];
  const float* be2 = (const float*)d_in[13];

  float* out = (float*)d_out;
  float* newxyz = out;
  float* newpts = out + (size_t)NBATCH * NPT * 3;

  char* ws = (char*)d_ws;
  // [0,67MB)    Y1 (dead after mm2) / P3 pooled 8MB (written by mm3, later)
  // [134,201MB) Y2
  unsigned short* Y1 = (unsigned short*)ws;
  float* P3 = (float*)ws;
  unsigned short* Y2 = (unsigned short*)(ws + 134217728);
  int*   gidx = (int*)  (ws + 201326592);
  float* psum = (float*)(ws + 203423744);
  float* psq  = (float*)(ws + 205520896);
  float* st   = (float*)(ws + 207618048);
  float* st1 = st, *st2 = st + 256, *st3 = st + 512;
  unsigned short* wb0 = (unsigned short*)(ws + 207621120);
  unsigned short* wb1 = (unsigned short*)(ws + 207621120 + 12288);
  unsigned short* wb2 = (unsigned short*)(ws + 207621120 + 12288 + 8192);

  prep_kernel<<<1, 256, 0, stream>>>(w0, w1, w2, wb0, wb1, wb2);
  fps_kernel<<<NBATCH, FPS_T, 0, stream>>>(xyz, newxyz);
  ballquery_kernel<<<(NBATCH * NPT) / 4, 256, 0, stream>>>(xyz, newxyz, gidx);
  mm1_mfma_kernel<<<MROWS / 64, 256, 0, stream>>>(xyz, points, newxyz, gidx, wb0, Y1, psum, psq);
  finalize_kernel<<<64, 256, 0, stream>>>(psum, psq, g0, be0, st1, 64, MROWS / 64);
  mm_mfma_kernel<64, 4><<<MROWS / 64, 256, 0, stream>>>(Y1, wb1, st1, Y2, psum, psq);
  finalize_kernel<<<64, 256, 0, stream>>>(psum, psq, g1, be1, st2, 64, MROWS / 64);
  mm3_pool_kernel<<<MROWS / 128, 512, 0, stream>>>(Y2, wb2, st2, P3, psum, psq);
  finalize_kernel<<<128, 256, 0, stream>>>(psum, psq, g2, be2, st3, 128, MROWS / 128);
  bn_relu_kernel<<<2048, 256, 0, stream>>>(P3, st3, newpts);
}

// Round 9
// 863.351 us; speedup vs baseline: 1.6685x; 1.0475x over previous
//
#include <hip/hip_runtime.h>
#include <hip/hip_bf16.h>
#include <cstdint>
#include <cstddef>

#define NPTS   4096
#define NPT    1024            // NPOINT (S)
#define NSAMP  32
#define NBATCH 16
#define MROWS  (NBATCH*NPT*NSAMP)   // 524288 rows for the conv layers
#define EPSV   1e-5f

typedef __attribute__((ext_vector_type(8))) short bfrag;   // 8 bf16 = 4 VGPRs
typedef __attribute__((ext_vector_type(4))) float f32x4;
typedef __attribute__((ext_vector_type(2))) float f32x2;

static __device__ __forceinline__ unsigned short f2bf(float f) {
  union { float f; unsigned u; } x; x.f = f;
  unsigned u = x.u;
  u += 0x7FFFu + ((u >> 16) & 1u);
  return (unsigned short)(u >> 16);
}
static __device__ __forceinline__ float bf2f(unsigned short h) {
  union { unsigned u; float f; } x; x.u = ((unsigned)h) << 16;
  return x.f;
}
// RNE f32x2 -> packed bf16x2 (single instruction)
static __device__ __forceinline__ unsigned cvt_pk_bf16(float lo, float hi) {
  unsigned r;
  asm("v_cvt_pk_bf16_f32 %0, %1, %2" : "=v"(r) : "v"(lo), "v"(hi));
  return r;
}

// ---------------------------------------------------------------------------
// Kernel 0: weights -> bf16. W0 is CHANNEL-PERMUTED to [pf(64) | relxyz(3) |
// zeros(29)] so mm1's gather is fully vectorized (dot product is invariant
// under a consistent permutation of the K axis).
// ---------------------------------------------------------------------------
__global__ __launch_bounds__(256) void prep_kernel(
    const float* __restrict__ w0, const float* __restrict__ w1,
    const float* __restrict__ w2, unsigned short* __restrict__ wb0,
    unsigned short* __restrict__ wb1, unsigned short* __restrict__ wb2) {
  const int tid = threadIdx.x;
  for (int i = tid; i < 64 * 96; i += 256) {
    const int o = i / 96, c = i % 96;
    float v;
    if (c < 64)      v = w0[o * 67 + 3 + c];   // point features
    else if (c < 67) v = w0[o * 67 + (c - 64)]; // rel xyz
    else             v = 0.f;
    wb0[i] = f2bf(v);
  }
  for (int i = tid; i < 64 * 64; i += 256) wb1[i] = f2bf(w1[i]);
  for (int i = tid; i < 128 * 64; i += 256) wb2[i] = f2bf(w2[i]);
}

// ---------------------------------------------------------------------------
// Kernel 1: farthest point sampling, v6 = r6 structure + float2-typed update
// loop. Plain float2 operators let LLVM emit v_pk_add/mul_f32 (VOP3P) with
// no asm marshalling; worst case it scalarizes to exactly the r6 code.
// fp contract(off) keeps mul+add separate (numpy association preserved:
// (dx^2+dy^2)+dz^2, all RN). Tie-break: pair .x preferred on tie, strict->
// chain over pairs/lanes/waves == global first-max.
// ---------------------------------------------------------------------------
#define FPS_T 256
#define PPT   (NPTS / FPS_T)   // 16 points = 8 pairs

template <int CTRL>
static __device__ __forceinline__ float dpp_max_step(float v) {
  int t = __builtin_amdgcn_update_dpp(0, __float_as_int(v), CTRL, 0xF, 0xF, true);
  return fmaxf(v, __int_as_float(t));
}

__global__ __launch_bounds__(FPS_T) void fps_kernel(
    const float* __restrict__ xyz, float* __restrict__ out_newxyz) {
  __shared__ __align__(16) float xs[NPTS];
  __shared__ __align__(16) float ys[NPTS];
  __shared__ __align__(16) float zs[NPTS];
  __shared__ __align__(16) float olds[NPT * 3];
  __shared__ __align__(16) uint2 sl[2][4];   // (bits(max), idx) per wave

  const int b = blockIdx.x;
  const int tid = threadIdx.x;
  const int wave = tid >> 6;
  const float* base = xyz + (size_t)b * NPTS * 3;
  for (int i = tid; i < NPTS; i += FPS_T) {
    xs[i] = base[3 * i + 0];
    ys[i] = base[3 * i + 1];
    zs[i] = base[3 * i + 2];
  }
  __syncthreads();

  const int p0 = tid * PPT;
  f32x2 px2[8], py2[8], pz2[8], d2[8];
  #pragma unroll
  for (int p = 0; p < 8; ++p) {
    px2[p] = f32x2{xs[p0 + 2 * p], xs[p0 + 2 * p + 1]};
    py2[p] = f32x2{ys[p0 + 2 * p], ys[p0 + 2 * p + 1]};
    pz2[p] = f32x2{zs[p0 + 2 * p], zs[p0 + 2 * p + 1]};
    d2[p] = f32x2{1e10f, 1e10f};
  }

  int cur = 0;
  for (int it = 0; it < NPT; ++it) {
    const float cx = xs[cur], cy = ys[cur], cz = zs[cur];
    if (tid == 0) {
      olds[3 * it + 0] = cx;
      olds[3 * it + 1] = cy;
      olds[3 * it + 2] = cz;
    }
    if (it == NPT - 1) break;

    float bestv = -1.f; int besti = p0;
    {
      #pragma clang fp contract(off)
      const f32x2 c2x = {cx, cx}, c2y = {cy, cy}, c2z = {cz, cz};
      #pragma unroll
      for (int p = 0; p < 8; ++p) {
        const f32x2 dx = px2[p] - c2x;
        const f32x2 dy = py2[p] - c2y;
        const f32x2 dz = pz2[p] - c2z;
        const f32x2 s = (dx * dx + dy * dy) + dz * dz;
        f32x2 nd = d2[p];
        nd.x = fminf(nd.x, s.x);
        nd.y = fminf(nd.y, s.y);
        d2[p] = nd;
        const float pmax = fmaxf(nd.x, nd.y);
        const bool yg = nd.y > nd.x;          // strict: .x wins ties
        const int pidx = p0 + 2 * p + (yg ? 1 : 0);
        const bool g = pmax > bestv;          // strict: earlier pair wins ties
        bestv = g ? pmax : bestv;
        besti = g ? pidx : besti;
      }
    }

    // wave-wide max VALUE (distances >= 0, bound_ctrl zero-fill safe)
    float m = bestv;
    m = dpp_max_step<0x111>(m);   // row_shr:1
    m = dpp_max_step<0x112>(m);   // row_shr:2
    m = dpp_max_step<0x114>(m);   // row_shr:4
    m = dpp_max_step<0x118>(m);   // row_shr:8
    m = dpp_max_step<0x142>(m);   // row_bcast:15
    m = dpp_max_step<0x143>(m);   // row_bcast:31  -> lane 63 holds wave max
    const float wmax =
        __int_as_float(__builtin_amdgcn_readlane(__float_as_int(m), 63));

    // lowest lane matching wave max == lowest index in wave
    const unsigned long long mask = __ballot(bestv == wmax);
    const int wl = __ffsll((long long)mask) - 1;
    const int widx = __builtin_amdgcn_readlane(besti, wl);

    const int buf = it & 1;
    if ((tid & 63) == 0)
      sl[buf][wave] = make_uint2(__float_as_uint(wmax), (unsigned)widx);
    __syncthreads();   // single barrier; double-buffered slots prevent WAR

    // all threads combine the 4 wave winners (2x ds_read_b128 broadcast)
    const uint4* p4 = (const uint4*)&sl[buf][0];
    const uint4 q0 = p4[0], q1 = p4[1];
    float bv; int bi;
    {
      bv = __uint_as_float(q0.x); bi = (int)q0.y;
      const float v1 = __uint_as_float(q0.z);
      if (v1 > bv) { bv = v1; bi = (int)q0.w; }
      const float v2 = __uint_as_float(q1.x);
      if (v2 > bv) { bv = v2; bi = (int)q1.y; }
      const float v3 = __uint_as_float(q1.z);
      if (v3 > bv) { bv = v3; bi = (int)q1.w; }
    }
    cur = bi;
  }

  __syncthreads();
  float* outb = out_newxyz + (size_t)b * NPT * 3;
  for (int i = tid; i < NPT * 3 / 4; i += FPS_T)
    *(float4*)&outb[4 * i] = *(const float4*)&olds[4 * i];
}

// ---------------------------------------------------------------------------
// Kernel 2: ball query (unchanged).
// ---------------------------------------------------------------------------
__global__ __launch_bounds__(256) void ballquery_kernel(
    const float* __restrict__ xyz, const float* __restrict__ newxyz,
    int* __restrict__ gidx) {
  const int gw = (int)((blockIdx.x * 256 + threadIdx.x) >> 6);
  const int lane = threadIdx.x & 63;
  const int b = gw >> 10, s = gw & 1023;
  const float* base = xyz + (size_t)b * NPTS * 3;
  const float* c = newxyz + (size_t)(b * NPT + s) * 3;
  const float cx = c[0], cy = c[1], cz = c[2];
  const float R2 = (float)(0.2 * 0.2);
  int* g = gidx + (size_t)(b * NPT + s) * NSAMP;

  int count = 0;
  int first = -1;
  for (int ch = 0; ch < NPTS / 64; ++ch) {
    const int i = ch * 64 + lane;
    const float dx = __fsub_rn(base[3 * i + 0], cx);
    const float dy = __fsub_rn(base[3 * i + 1], cy);
    const float dz = __fsub_rn(base[3 * i + 2], cz);
    const float d = __fadd_rn(__fadd_rn(__fmul_rn(dx, dx), __fmul_rn(dy, dy)),
                              __fmul_rn(dz, dz));
    const bool pred = !(d > R2);
    const unsigned long long mask = __ballot(pred);
    if (mask) {
      if (count == 0) first = ch * 64 + (__ffsll((long long)mask) - 1);
      const int rank = __popcll(mask & ((1ull << lane) - 1ull));
      const int pos = count + rank;
      if (pred && pos < NSAMP) g[pos] = i;
      count += (int)__popcll(mask);
      if (count >= NSAMP) break;
    }
  }
  if (first < 0) first = 0;
  for (int j = count + lane; j < NSAMP; j += 64) g[j] = first;
}

// ---------------------------------------------------------------------------
// Kernel 3: layer-1 MFMA matmul, permuted-channel gather: thread q of each
// row loads pf[16q..16q+16) as 4x dwordx4 (aligned), writes 2x b128 to LDS;
// q==0 adds relxyz at ch 64-66 + zero pad to 95. No scalar-load storm.
// ---------------------------------------------------------------------------
__global__ __launch_bounds__(256) void mm1_mfma_kernel(
    const float* __restrict__ xyz, const float* __restrict__ points,
    const float* __restrict__ newxyz, const int* __restrict__ gidx,
    const unsigned short* __restrict__ Wb, unsigned short* __restrict__ Y,
    float* __restrict__ psum, float* __restrict__ psq) {
  constexpr int KP = 104;
  __shared__ __align__(16) unsigned short As[64 * KP];
  __shared__ __align__(16) unsigned short ly[64 * 64];
  __shared__ float ssum[64], ssq[64];
  const int tid = threadIdx.x, bid = blockIdx.x;
  const size_t r0 = (size_t)bid * 64;

  {
    const int row = tid >> 2, q = tid & 3;
    const int gs = bid * 2 + (row >> 5);
    const int b = gs >> 10;
    const int k = row & 31;
    const int gpt = gidx[(size_t)gs * NSAMP + k];
    const float* pf = points + ((size_t)b * NPTS + gpt) * 64 + 16 * q;
    float f[16];
    #pragma unroll
    for (int i = 0; i < 4; ++i)
      *(float4*)&f[4 * i] = *(const float4*)&pf[4 * i];
    uint4 u0, u1;
    u0.x = cvt_pk_bf16(f[0], f[1]);   u0.y = cvt_pk_bf16(f[2], f[3]);
    u0.z = cvt_pk_bf16(f[4], f[5]);   u0.w = cvt_pk_bf16(f[6], f[7]);
    u1.x = cvt_pk_bf16(f[8], f[9]);   u1.y = cvt_pk_bf16(f[10], f[11]);
    u1.z = cvt_pk_bf16(f[12], f[13]); u1.w = cvt_pk_bf16(f[14], f[15]);
    uint4* dst = (uint4*)&As[row * KP + 16 * q];
    dst[0] = u0; dst[1] = u1;
    if (q == 0) {
      const float* px = xyz + ((size_t)b * NPTS + gpt) * 3;
      const float* pc = newxyz + (size_t)gs * 3;
      const float rx = px[0] - pc[0];
      const float ry = px[1] - pc[1];
      const float rz = px[2] - pc[2];
      uint4* d2 = (uint4*)&As[row * KP + 64];
      d2[0] = uint4{cvt_pk_bf16(rx, ry), cvt_pk_bf16(rz, 0.f), 0u, 0u};
      d2[1] = uint4{0u, 0u, 0u, 0u};
      d2[2] = uint4{0u, 0u, 0u, 0u};
      d2[3] = uint4{0u, 0u, 0u, 0u};
    }
  }
  if (tid < 64) { ssum[tid] = 0.f; ssq[tid] = 0.f; }
  __syncthreads();

  const int wave = tid >> 6, lane = tid & 63;
  const int l15 = lane & 15, kq = lane >> 4;
  const unsigned short* abase = &As[(wave * 16 + l15) * KP + kq * 8];
  const bfrag a0 = *(const bfrag*)abase;
  const bfrag a1 = *(const bfrag*)(abase + 32);
  const bfrag a2 = *(const bfrag*)(abase + 64);

  #pragma unroll
  for (int nt = 0; nt < 4; ++nt) {
    const unsigned short* wsrc = Wb + (size_t)(nt * 16 + l15) * 96 + kq * 8;
    const bfrag b0 = *(const bfrag*)wsrc;
    const bfrag b1 = *(const bfrag*)(wsrc + 32);
    const bfrag b2 = *(const bfrag*)(wsrc + 64);
    f32x4 acc = {0.f, 0.f, 0.f, 0.f};
    acc = __builtin_amdgcn_mfma_f32_16x16x32_bf16(a0, b0, acc, 0, 0, 0);
    acc = __builtin_amdgcn_mfma_f32_16x16x32_bf16(a1, b1, acc, 0, 0, 0);
    acc = __builtin_amdgcn_mfma_f32_16x16x32_bf16(a2, b2, acc, 0, 0, 0);

    float s = acc[0] + acc[1] + acc[2] + acc[3];
    float q = acc[0]*acc[0] + acc[1]*acc[1] + acc[2]*acc[2] + acc[3]*acc[3];
    s += __shfl_xor(s, 16); q += __shfl_xor(q, 16);
    s += __shfl_xor(s, 32); q += __shfl_xor(q, 32);
    if (kq == 0) {
      atomicAdd(&ssum[nt * 16 + l15], s);
      atomicAdd(&ssq [nt * 16 + l15], q);
    }
    const unsigned p01 = cvt_pk_bf16(acc[0], acc[1]);
    const unsigned p23 = cvt_pk_bf16(acc[2], acc[3]);
    const int colo = nt * 16 + l15;
    const int rbase = wave * 16 + kq * 4;
    ly[(rbase + 0) * 64 + colo] = (unsigned short)(p01 & 0xffffu);
    ly[(rbase + 1) * 64 + colo] = (unsigned short)(p01 >> 16);
    ly[(rbase + 2) * 64 + colo] = (unsigned short)(p23 & 0xffffu);
    ly[(rbase + 3) * 64 + colo] = (unsigned short)(p23 >> 16);
  }
  __syncthreads();
  {
    const uint4* lsrc = (const uint4*)ly;
    uint4* gdst = (uint4*)(Y + r0 * 64);
    #pragma unroll
    for (int i = tid; i < 64 * 64 * 2 / 16; i += 256) gdst[i] = lsrc[i];
  }
  if (tid < 64) {
    psum[(size_t)bid * 64 + tid] = ssum[tid];
    psq [(size_t)bid * 64 + tid] = ssq [tid];
  }
}

// ---------------------------------------------------------------------------
// Layer 2 MFMA (unchanged).
// ---------------------------------------------------------------------------
static __device__ __forceinline__ bfrag affine_relu_frag(
    const unsigned short* __restrict__ src, const float* __restrict__ st,
    int c0) {
  union { bfrag f; unsigned u[4]; } r;
  const uint4 raw = *(const uint4*)src;
  const unsigned w[4] = {raw.x, raw.y, raw.z, raw.w};
  #pragma unroll
  for (int p = 0; p < 4; ++p) {
    const int c = c0 + 2 * p;
    float lo = bf2f((unsigned short)(w[p] & 0xffffu));
    float hi = bf2f((unsigned short)(w[p] >> 16));
    lo = fmaxf(fmaf(lo, st[2 * c + 0], st[2 * c + 1]), 0.f);
    hi = fmaxf(fmaf(hi, st[2 * c + 2], st[2 * c + 3]), 0.f);
    r.u[p] = cvt_pk_bf16(lo, hi);
  }
  return r.f;
}

template <int COUT, int WAVES>
__global__ __launch_bounds__(WAVES * 64) void mm_mfma_kernel(
    const unsigned short* __restrict__ Xin, const unsigned short* __restrict__ Wb,
    const float* __restrict__ stin, unsigned short* __restrict__ Y,
    float* __restrict__ psum, float* __restrict__ psq) {
  constexpr int NT = COUT / 16;
  constexpr int ROWS = WAVES * 16;
  __shared__ float ssum[COUT], ssq[COUT];
  __shared__ __align__(16) unsigned short ly[ROWS * COUT];
  const int tid = threadIdx.x, bid = blockIdx.x;
  const int wave = tid >> 6, lane = tid & 63;
  const int l15 = lane & 15, kq = lane >> 4;
  const size_t r0 = (size_t)bid * ROWS;
  if (tid < COUT) { ssum[tid] = 0.f; ssq[tid] = 0.f; }

  const int arow = wave * 16 + l15;
  const unsigned short* asrc = Xin + (r0 + arow) * 64 + kq * 8;
  const bfrag a0 = affine_relu_frag(asrc, stin, kq * 8);
  const bfrag a1 = affine_relu_frag(asrc + 32, stin, 32 + kq * 8);
  __syncthreads();

  #pragma unroll
  for (int nt = 0; nt < NT; ++nt) {
    const unsigned short* wsrc = Wb + (size_t)(nt * 16 + l15) * 64 + kq * 8;
    const bfrag b0 = *(const bfrag*)wsrc;
    const bfrag b1 = *(const bfrag*)(wsrc + 32);
    f32x4 acc = {0.f, 0.f, 0.f, 0.f};
    acc = __builtin_amdgcn_mfma_f32_16x16x32_bf16(a0, b0, acc, 0, 0, 0);
    acc = __builtin_amdgcn_mfma_f32_16x16x32_bf16(a1, b1, acc, 0, 0, 0);

    float s = acc[0] + acc[1] + acc[2] + acc[3];
    float q = acc[0]*acc[0] + acc[1]*acc[1] + acc[2]*acc[2] + acc[3]*acc[3];
    s += __shfl_xor(s, 16); q += __shfl_xor(q, 16);
    s += __shfl_xor(s, 32); q += __shfl_xor(q, 32);
    if (kq == 0) {
      atomicAdd(&ssum[nt * 16 + l15], s);
      atomicAdd(&ssq [nt * 16 + l15], q);
    }
    const unsigned p01 = cvt_pk_bf16(acc[0], acc[1]);
    const unsigned p23 = cvt_pk_bf16(acc[2], acc[3]);
    const int colo = nt * 16 + l15;
    const int rbase = wave * 16 + kq * 4;
    ly[(rbase + 0) * COUT + colo] = (unsigned short)(p01 & 0xffffu);
    ly[(rbase + 1) * COUT + colo] = (unsigned short)(p01 >> 16);
    ly[(rbase + 2) * COUT + colo] = (unsigned short)(p23 & 0xffffu);
    ly[(rbase + 3) * COUT + colo] = (unsigned short)(p23 >> 16);
  }
  __syncthreads();
  {
    const uint4* lsrc = (const uint4*)ly;
    uint4* gdst = (uint4*)(Y + r0 * COUT);
    #pragma unroll
    for (int i = tid; i < ROWS * COUT * 2 / 16; i += WAVES * 64) gdst[i] = lsrc[i];
  }
  if (tid < COUT) {
    psum[(size_t)bid * COUT + tid] = ssum[tid];
    psq [(size_t)bid * COUT + tid] = ssq [tid];
  }
}

// ---------------------------------------------------------------------------
// Layer 3 MFMA + fused maxpool (unchanged from r8).
// ---------------------------------------------------------------------------
__global__ __launch_bounds__(512) void mm3_pool_kernel(
    const unsigned short* __restrict__ Xin, const unsigned short* __restrict__ Wb,
    const float* __restrict__ stin, float* __restrict__ pooled,
    float* __restrict__ psum, float* __restrict__ psq) {
  constexpr int COUT = 128, NT = 8;
  __shared__ float ssum[COUT], ssq[COUT];
  __shared__ float pm[8][COUT];           // per-wave 16-row max
  const int tid = threadIdx.x, bid = blockIdx.x;
  const int wave = tid >> 6, lane = tid & 63;
  const int l15 = lane & 15, kq = lane >> 4;
  const size_t r0 = (size_t)bid * 128;
  if (tid < COUT) { ssum[tid] = 0.f; ssq[tid] = 0.f; }

  const int arow = wave * 16 + l15;
  const unsigned short* asrc = Xin + (r0 + arow) * 64 + kq * 8;
  const bfrag a0 = affine_relu_frag(asrc, stin, kq * 8);
  const bfrag a1 = affine_relu_frag(asrc + 32, stin, 32 + kq * 8);
  __syncthreads();

  #pragma unroll
  for (int nt = 0; nt < NT; ++nt) {
    const unsigned short* wsrc = Wb + (size_t)(nt * 16 + l15) * 64 + kq * 8;
    const bfrag b0 = *(const bfrag*)wsrc;
    const bfrag b1 = *(const bfrag*)(wsrc + 32);
    f32x4 acc = {0.f, 0.f, 0.f, 0.f};
    acc = __builtin_amdgcn_mfma_f32_16x16x32_bf16(a0, b0, acc, 0, 0, 0);
    acc = __builtin_amdgcn_mfma_f32_16x16x32_bf16(a1, b1, acc, 0, 0, 0);

    float s = acc[0] + acc[1] + acc[2] + acc[3];
    float q = acc[0]*acc[0] + acc[1]*acc[1] + acc[2]*acc[2] + acc[3]*acc[3];
    s += __shfl_xor(s, 16); q += __shfl_xor(q, 16);
    s += __shfl_xor(s, 32); q += __shfl_xor(q, 32);
    float mx = fmaxf(fmaxf(acc[0], acc[1]), fmaxf(acc[2], acc[3]));
    mx = fmaxf(mx, __shfl_xor(mx, 16));
    mx = fmaxf(mx, __shfl_xor(mx, 32));
    if (kq == 0) {
      atomicAdd(&ssum[nt * 16 + l15], s);
      atomicAdd(&ssq [nt * 16 + l15], q);
      pm[wave][nt * 16 + l15] = mx;
    }
  }
  __syncthreads();
  {
    const int g = tid >> 7, col = tid & 127;
    const float v = fmaxf(pm[2 * g][col], pm[2 * g + 1][col]);
    pooled[(r0 >> 5) * COUT + g * COUT + col] = v;
  }
  if (tid < COUT) {
    psum[(size_t)bid * COUT + tid] = ssum[tid];
    psq [(size_t)bid * COUT + tid] = ssq [tid];
  }
}

// ---------------------------------------------------------------------------
// BN stats finalize (unchanged).
// ---------------------------------------------------------------------------
__global__ __launch_bounds__(256) void finalize_kernel(
    const float* __restrict__ psum, const float* __restrict__ psq,
    const float* __restrict__ gam, const float* __restrict__ bet,
    float* __restrict__ st, int C, int nb) {
  const int c = blockIdx.x, tid = threadIdx.x;
  float s = 0.f, q = 0.f;
  for (int i = tid; i < nb; i += 256) {
    s += psum[(size_t)i * C + c];
    q += psq [(size_t)i * C + c];
  }
  #pragma unroll
  for (int off = 32; off > 0; off >>= 1) {
    s += __shfl_down(s, off);
    q += __shfl_down(q, off);
  }
  __shared__ float as_[4], aq_[4];
  if ((tid & 63) == 0) { as_[tid >> 6] = s; aq_[tid >> 6] = q; }
  __syncthreads();
  if (tid == 0) {
    s = as_[0] + as_[1] + as_[2] + as_[3];
    q = aq_[0] + aq_[1] + aq_[2] + aq_[3];
    const float invM = 1.f / (float)MROWS;
    const float mean = s * invM;
    const float var = q * invM - mean * mean;
    const float inv = 1.f / sqrtf(var + EPSV);
    const float sc = gam[c] * inv;
    st[2 * c + 0] = sc;
    st[2 * c + 1] = bet[c] - mean * sc;
  }
}

// ---------------------------------------------------------------------------
// Epilogue: BN3 affine + relu on the pooled tensor -> new_points.
// ---------------------------------------------------------------------------
__global__ __launch_bounds__(256) void bn_relu_kernel(
    const float* __restrict__ pooled, const float* __restrict__ st,
    float* __restrict__ out) {
  __shared__ float s_st[256];
  const int tid = threadIdx.x;
  s_st[tid] = st[tid];
  __syncthreads();
  const int n4 = NBATCH * NPT * 128 / 4;
  for (int i = blockIdx.x * 256 + tid; i < n4; i += gridDim.x * 256) {
    float4 v = ((const float4*)pooled)[i];
    const int c0 = (i * 4) & 127;
    v.x = fmaxf(fmaf(v.x, s_st[2 * c0 + 0], s_st[2 * c0 + 1]), 0.f);
    v.y = fmaxf(fmaf(v.y, s_st[2 * c0 + 2], s_st[2 * c0 + 3]), 0.f);
    v.z = fmaxf(fmaf(v.z, s_st[2 * c0 + 4], s_st[2 * c0 + 5]), 0.f);
    v.w = fmaxf(fmaf(v.w, s_st[2 * c0 + 6], s_st[2 * c0 + 7]), 0.f);
    ((float4*)out)[i] = v;
  }
}

// ---------------------------------------------------------------------------
extern "C" void kernel_launch(void* const* d_in, const int* in_sizes, int n_in,
                              void* d_out, int out_size, void* d_ws, size_t ws_size,
                              hipStream_t stream) {
  (void)in_sizes; (void)n_in; (void)out_size; (void)ws_size;
  const float* xyz    = (const float*)d_in[0];
  const float* points = (const float*)d_in[1];
  const float* w0 = (const float*)d_in[2];
  const float* g0 = (const float*)d_in[4];
  const float* be0 = (const float*)d_in[5];
  const float* w1 = (const float*)d_in[6];
  const float* g1 = (const float*)d_in[8];
  const float* be1 = (const float*)d_in[9];
  const float* w2 = (const float*)d_in[10];
  const float* g2 = (const float*)d_in[12];
  const float* be2 = (const float*)d_in[13];

  float* out = (float*)d_out;
  float* newxyz = out;
  float* newpts = out + (size_t)NBATCH * NPT * 3;

  char* ws = (char*)d_ws;
  unsigned short* Y1 = (unsigned short*)ws;
  float* P3 = (float*)ws;
  unsigned short* Y2 = (unsigned short*)(ws + 134217728);
  int*   gidx = (int*)  (ws + 201326592);
  float* psum = (float*)(ws + 203423744);
  float* psq  = (float*)(ws + 205520896);
  float* st   = (float*)(ws + 207618048);
  float* st1 = st, *st2 = st + 256, *st3 = st + 512;
  unsigned short* wb0 = (unsigned short*)(ws + 207621120);
  unsigned short* wb1 = (unsigned short*)(ws + 207621120 + 12288);
  unsigned short* wb2 = (unsigned short*)(ws + 207621120 + 12288 + 8192);

  prep_kernel<<<1, 256, 0, stream>>>(w0, w1, w2, wb0, wb1, wb2);
  fps_kernel<<<NBATCH, FPS_T, 0, stream>>>(xyz, newxyz);
  ballquery_kernel<<<(NBATCH * NPT) / 4, 256, 0, stream>>>(xyz, newxyz, gidx);
  mm1_mfma_kernel<<<MROWS / 64, 256, 0, stream>>>(xyz, points, newxyz, gidx, wb0, Y1, psum, psq);
  finalize_kernel<<<64, 256, 0, stream>>>(psum, psq, g0, be0, st1, 64, MROWS / 64);
  mm_mfma_kernel<64, 4><<<MROWS / 64, 256, 0, stream>>>(Y1, wb1, st1, Y2, psum, psq);
  finalize_kernel<<<64, 256, 0, stream>>>(psum, psq, g1, be1, st2, 64, MROWS / 64);
  mm3_pool_kernel<<<MROWS / 128, 512, 0, stream>>>(Y2, wb2, st2, P3, psum, psq);
  finalize_kernel<<<128, 256, 0, stream>>>(psum, psq, g2, be2, st3, 128, MROWS / 128);
  bn_relu_kernel<<<2048, 256, 0, stream>>>(P3, st3, newpts);
}